// Round 9
// baseline (393.051 us; speedup 1.0000x reference)
//
#include <hip/hip_runtime.h>

// NRI MLP decoder, single step. B=8, N=32, T=256, D=4, E=992, K=2, H=64, M=64, NH=128.
// Edge e: receiver i=e/31, jj=e%31, sender j = jj<i ? jj : jj+1.
// h1 = relu(S[j]+R[i]), S = x@W1[k][0:4]+b1 (senders first), R = x@W1[k][4:8].
// msg = relu(h1@W2[k]+b2[k]); agg[i] += msg*g[e,k]
// aug=[agg|x|0pad] -> relu(@[Wo1_agg;Wo1_x]+bo1) -> relu(@Wo2+bo2) -> @Wo3+bo3; out=x+pred.
// GEMMs via v_mfma_f32_16x16x32_f16. 512-thread blocks (8 waves), one t per block:
// edge GEMM split by receiver (4/wave), node MLP split by NH (16 cols/wave).
// 16 waves/CU (vs 12 in the 4-wave variant) — latency-bound kernel, concurrency is king.
// MFMA layout (16x16x32): A: row=l&15, k=8*(l>>4)+e; B: col=l&15, k=8*(l>>4)+e;
//                         D: col=l&15, row=4*(l>>4)+reg.

typedef _Float16 f16x8 __attribute__((ext_vector_type(8)));
typedef __fp16   f16x2 __attribute__((ext_vector_type(2)));   // cvt_pkrtz return type
typedef float    f32x4 __attribute__((ext_vector_type(4)));

union ABfrag { f16x8 v; f16x2 h[4]; };

__global__ __launch_bounds__(512, 4)
void nri_fused(const float* __restrict__ inputs,
               const float* __restrict__ rgraph,
               const float* __restrict__ W1,  const float* __restrict__ b1,
               const float* __restrict__ W2,  const float* __restrict__ b2,
               const float* __restrict__ Wo1, const float* __restrict__ bo1,
               const float* __restrict__ Wo2, const float* __restrict__ bo2,
               const float* __restrict__ Wo3, const float* __restrict__ bo3,
               float* __restrict__ out)
{
    // floats: x 0(128) | g 128(1984) | S 2112(32x68) | R 4288(32x68) |
    //         aug 6464(32x100) | h_l 9664(32x136 halves = 2176 fl) | wo3 11840(516)
    // p2 overlays S/R: 2112(32x132=4224 <= 4352).  Total 12356 fl = 49.4KB -> 2 blk/CU.
    __shared__ float smem[12356];
    float* x_l = smem;
    float* g_l = smem + 128;
    float* S   = smem + 2112;
    float* R   = smem + 4288;
    float* aug = smem + 6464;
    _Float16* h_l = reinterpret_cast<_Float16*>(smem + 9664);
    float* wo3_l = smem + 11840;    // 512 Wo3 + 4 bo3
    float* p2  = smem + 2112;

    const int tid  = threadIdx.x;
    const int b    = blockIdx.x >> 8;
    const int t    = blockIdx.x & 255;
    const int w    = tid >> 6;      // wave 0..7
    const int lane = tid & 63;
    const int q    = lane & 15;
    const int g4   = lane >> 4;
    const int c0   = 16 * w;        // wave's 16-col slice of NH=128

    // ---- stage x, g, Wo3/bo3, aug zero pad (cols 68..95) ----
    if (tid < 32)
        reinterpret_cast<float4*>(x_l)[tid] =
            *reinterpret_cast<const float4*>(
                inputs + ((size_t)(b * 32 + tid) * 256 + t) * 4);
    for (int idx = tid; idx < 1984; idx += 512) g_l[idx] = rgraph[idx];
    if (tid < 512) { if (tid < 512) wo3_l[tid] = Wo3[tid]; }
    if (tid < 4) wo3_l[512 + tid] = bo3[tid];
    for (int idx = tid; idx < 896; idx += 512) {
        const int n = idx >> 5, c = idx & 31;
        if (c < 28) aug[n * 100 + 68 + c] = 0.f;
    }

    // ---- weight fragments (registers) ----
    ABfrag w2f[2][4][2];
    float bb[2][4];
    #pragma unroll
    for (int k = 0; k < 2; ++k)
        #pragma unroll
        for (int n = 0; n < 4; ++n) {
            bb[k][n] = b2[k * 64 + 16 * n + q];
            #pragma unroll
            for (int s = 0; s < 2; ++s)
                #pragma unroll
                for (int e2 = 0; e2 < 4; ++e2) {
                    const int ka = 32 * s + 8 * g4 + 2 * e2;
                    w2f[k][n][s].h[e2] = __builtin_amdgcn_cvt_pkrtz(
                        W2[k * 4096 + ka * 64 + 16 * n + q],
                        W2[k * 4096 + (ka + 1) * 64 + 16 * n + q]);
                }
        }
    ABfrag bf1[3];
    const int colw = c0 + q;
    const float bo1f = bo1[colw];
    #pragma unroll
    for (int s = 0; s < 3; ++s)
        #pragma unroll
        for (int e2 = 0; e2 < 4; ++e2) {
            const int ka = 32 * s + 8 * g4 + 2 * e2;
            const int kb = ka + 1;
            const float v0 = (ka < 64) ? Wo1[(4 + ka) * 128 + colw]
                           : ((ka < 68) ? Wo1[(ka - 64) * 128 + colw] : 0.f);
            const float v1 = (kb < 64) ? Wo1[(4 + kb) * 128 + colw]
                           : ((kb < 68) ? Wo1[(kb - 64) * 128 + colw] : 0.f);
            bf1[s].h[e2] = __builtin_amdgcn_cvt_pkrtz(v0, v1);
        }
    ABfrag bf2[4];
    const float bo2f = bo2[colw];
    #pragma unroll
    for (int s = 0; s < 4; ++s)
        #pragma unroll
        for (int e2 = 0; e2 < 4; ++e2) {
            const int ka = 32 * s + 8 * g4 + 2 * e2;
            bf2[s].h[e2] = __builtin_amdgcn_cvt_pkrtz(
                Wo2[ka * 128 + colw], Wo2[(ka + 1) * 128 + colw]);
        }

    __syncthreads();                           // x_l visible
    if (tid < 128) {                           // aug x-columns from LDS
        const int n = tid >> 2, c = tid & 3;
        aug[n * 100 + 64 + c] = x_l[n * 4 + c];
    }

    float agg_acc[4];
    #pragma unroll
    for (int rr = 0; rr < 4; ++rr) agg_acc[rr] = 0.f;

    for (int k = 0; k < 2; ++k) {
        if (k == 1) __syncthreads();           // edge reads of k=0 S/R done
        // ---- stage S (sender proj + b1), R (receiver proj), stride 68 ----
        for (int idx = tid; idx < 2048; idx += 512) {
            const int j = idx >> 6, kk = idx & 63;
            const float4 xj = reinterpret_cast<const float4*>(x_l)[j];
            const float* wp = W1 + k * 512 + kk;
            float s = b1[k * 64 + kk], r = 0.f;
            s = fmaf(xj.x, wp[0],   s);  r = fmaf(xj.x, wp[256], r);
            s = fmaf(xj.y, wp[64],  s);  r = fmaf(xj.y, wp[320], r);
            s = fmaf(xj.z, wp[128], s);  r = fmaf(xj.z, wp[384], r);
            s = fmaf(xj.w, wp[192], s);  r = fmaf(xj.w, wp[448], r);
            S[j * 68 + kk] = s;
            R[j * 68 + kk] = r;
        }
        __syncthreads();                       // S,R visible

        // ---- per-receiver edge GEMM (4 receivers per wave), no barriers ----
        #pragma unroll
        for (int rr = 0; rr < 4; ++rr) {
            const int i = w * 4 + rr;
            float4 Rv[2][2];
            #pragma unroll
            for (int s = 0; s < 2; ++s) {
                const float* rp = R + i * 68 + 32 * s + 8 * g4;
                Rv[s][0] = *reinterpret_cast<const float4*>(rp);
                Rv[s][1] = *reinterpret_cast<const float4*>(rp + 4);
            }
            float part[4] = {0.f, 0.f, 0.f, 0.f};
            #pragma unroll
            for (int m = 0; m < 2; ++m) {      // m-sequential: smaller live set
                const int r = 16 * m + q;
                const int j = (r == 31) ? 0 : ((r < i) ? r : r + 1);
                ABfrag af[2];
                #pragma unroll
                for (int s = 0; s < 2; ++s) {
                    const float* sp = S + j * 68 + 32 * s + 8 * g4;
                    const float4 s0 = *reinterpret_cast<const float4*>(sp);
                    const float4 s1 = *reinterpret_cast<const float4*>(sp + 4);
                    af[s].h[0] = __builtin_amdgcn_cvt_pkrtz(
                        fmaxf(s0.x + Rv[s][0].x, 0.f), fmaxf(s0.y + Rv[s][0].y, 0.f));
                    af[s].h[1] = __builtin_amdgcn_cvt_pkrtz(
                        fmaxf(s0.z + Rv[s][0].z, 0.f), fmaxf(s0.w + Rv[s][0].w, 0.f));
                    af[s].h[2] = __builtin_amdgcn_cvt_pkrtz(
                        fmaxf(s1.x + Rv[s][1].x, 0.f), fmaxf(s1.y + Rv[s][1].y, 0.f));
                    af[s].h[3] = __builtin_amdgcn_cvt_pkrtz(
                        fmaxf(s1.z + Rv[s][1].z, 0.f), fmaxf(s1.w + Rv[s][1].w, 0.f));
                }
                f32x4 acc[4];
                #pragma unroll
                for (int n = 0; n < 4; ++n) {
                    acc[n][0] = bb[k][n]; acc[n][1] = bb[k][n];
                    acc[n][2] = bb[k][n]; acc[n][3] = bb[k][n];
                }
                #pragma unroll
                for (int s = 0; s < 2; ++s)
                    #pragma unroll
                    for (int n = 0; n < 4; ++n)
                        acc[n] = __builtin_amdgcn_mfma_f32_16x16x32_f16(
                            af[s].v, w2f[k][n][s].v, acc[n], 0, 0, 0);
                #pragma unroll
                for (int reg = 0; reg < 4; ++reg) {
                    const int row = 16 * m + 4 * g4 + reg;
                    const float gv = (row < 31) ? g_l[(31 * i + row) * 2 + k] : 0.f;
                    #pragma unroll
                    for (int n = 0; n < 4; ++n)
                        part[n] = fmaf(fmaxf(acc[n][reg], 0.f), gv, part[n]);
                }
            }
            #pragma unroll
            for (int n = 0; n < 4; ++n) {
                part[n] += __shfl_xor(part[n], 16);
                part[n] += __shfl_xor(part[n], 32);
            }
            const float v = (g4 == 0) ? part[0] : (g4 == 1) ? part[1]
                          : (g4 == 2) ? part[2] : part[3];
            agg_acc[rr] += v;
        }
    }

    // ---- agg -> aug cols 0..63 ----
    #pragma unroll
    for (int rr = 0; rr < 4; ++rr)
        aug[(w * 4 + rr) * 100 + 16 * g4 + q] = agg_acc[rr];
    __syncthreads();

    // ---- node layer 1: aug(32x96) @ bf1 -> h cols c0..c0+15 (fp16, stride 136) ----
    {
        f32x4 acc[2];
        #pragma unroll
        for (int m = 0; m < 2; ++m) {
            acc[m][0] = bo1f; acc[m][1] = bo1f; acc[m][2] = bo1f; acc[m][3] = bo1f;
        }
        #pragma unroll
        for (int s = 0; s < 3; ++s) {
            ABfrag afr[2];
            #pragma unroll
            for (int m = 0; m < 2; ++m) {
                const float* ap = aug + (16 * m + q) * 100 + 32 * s + 8 * g4;
                const float4 a0 = *reinterpret_cast<const float4*>(ap);
                const float4 a1 = *reinterpret_cast<const float4*>(ap + 4);
                afr[m].h[0] = __builtin_amdgcn_cvt_pkrtz(a0.x, a0.y);
                afr[m].h[1] = __builtin_amdgcn_cvt_pkrtz(a0.z, a0.w);
                afr[m].h[2] = __builtin_amdgcn_cvt_pkrtz(a1.x, a1.y);
                afr[m].h[3] = __builtin_amdgcn_cvt_pkrtz(a1.z, a1.w);
            }
            #pragma unroll
            for (int m = 0; m < 2; ++m)
                acc[m] = __builtin_amdgcn_mfma_f32_16x16x32_f16(
                    afr[m].v, bf1[s].v, acc[m], 0, 0, 0);
        }
        #pragma unroll
        for (int m = 0; m < 2; ++m)
            #pragma unroll
            for (int reg = 0; reg < 4; ++reg) {
                const int row = 16 * m + 4 * g4 + reg;
                h_l[row * 136 + colw] = (_Float16)fmaxf(acc[m][reg], 0.f);
            }
    }
    __syncthreads();

    // ---- node layer 2: h(32x128 fp16) @ bf2 -> p2 cols c0..c0+15 (stride 132) ----
    {
        f32x4 acc[2];
        #pragma unroll
        for (int m = 0; m < 2; ++m) {
            acc[m][0] = bo2f; acc[m][1] = bo2f; acc[m][2] = bo2f; acc[m][3] = bo2f;
        }
        #pragma unroll
        for (int s = 0; s < 4; ++s) {
            f16x8 afr[2];
            #pragma unroll
            for (int m = 0; m < 2; ++m)
                afr[m] = *reinterpret_cast<const f16x8*>(
                    h_l + (16 * m + q) * 136 + 32 * s + 8 * g4);
            #pragma unroll
            for (int m = 0; m < 2; ++m)
                acc[m] = __builtin_amdgcn_mfma_f32_16x16x32_f16(
                    afr[m], bf2[s].v, acc[m], 0, 0, 0);
        }
        #pragma unroll
        for (int m = 0; m < 2; ++m)
            #pragma unroll
            for (int reg = 0; reg < 4; ++reg) {
                const int row = 16 * m + 4 * g4 + reg;
                p2[row * 132 + colw] = fmaxf(acc[m][reg], 0.f);
            }
    }
    __syncthreads();

    // ---- layer 3 (fp32 VALU, Wo3 from LDS) + residual + store (skip t==255) ----
    if (tid < 128 && t < 255) {
        const int rr3 = tid >> 2;
        const int dd  = tid & 3;
        float a0 = 0.f, a1 = 0.f, a2 = 0.f, a3 = 0.f;
        const float* pr = p2 + rr3 * 132;
        for (int d = 0; d < 128; d += 4) {
            a0 = fmaf(pr[d + 0], wo3_l[(d + 0) * 4 + dd], a0);
            a1 = fmaf(pr[d + 1], wo3_l[(d + 1) * 4 + dd], a1);
            a2 = fmaf(pr[d + 2], wo3_l[(d + 2) * 4 + dd], a2);
            a3 = fmaf(pr[d + 3], wo3_l[(d + 3) * 4 + dd], a3);
        }
        const float pred = ((a0 + a1) + (a2 + a3)) + wo3_l[512 + dd];
        out[((size_t)(b * 32 + rr3) * 255 + t) * 4 + dd] = x_l[rr3 * 4 + dd] + pred;
    }
}

__global__ void copy_relgraph(const float* __restrict__ g, float* __restrict__ out2)
{
    const int idx = blockIdx.x * 256 + threadIdx.x;
    if (idx < 15872) out2[idx] = g[idx % 1984];
}

extern "C" void kernel_launch(void* const* d_in, const int* in_sizes, int n_in,
                              void* d_out, int out_size, void* d_ws, size_t ws_size,
                              hipStream_t stream)
{
    (void)in_sizes; (void)n_in; (void)d_ws; (void)ws_size; (void)out_size;
    const float* inputs    = (const float*)d_in[0];
    const float* rel_graph = (const float*)d_in[3];
    const float* W1  = (const float*)d_in[4];
    const float* b1  = (const float*)d_in[5];
    const float* W2  = (const float*)d_in[6];
    const float* b2  = (const float*)d_in[7];
    const float* Wo1 = (const float*)d_in[8];
    const float* bo1 = (const float*)d_in[9];
    const float* Wo2 = (const float*)d_in[10];
    const float* bo2 = (const float*)d_in[11];
    const float* Wo3 = (const float*)d_in[12];
    const float* bo3 = (const float*)d_in[13];
    float* out = (float*)d_out;

    nri_fused<<<2048, 512, 0, stream>>>(inputs, rel_graph, W1, b1, W2, b2,
                                        Wo1, bo1, Wo2, bo2, Wo3, bo3, out);
    copy_relgraph<<<62, 256, 0, stream>>>(rel_graph, out + 261120);
}

// Round 12
// 257.363 us; speedup vs baseline: 1.5272x; 1.5272x over previous
//
#include <hip/hip_runtime.h>

// NRI MLP decoder, single step. B=8, N=32, T=256, D=4, E=992, K=2, H=64, M=64, NH=128.
// Edge e: receiver i=e/31, jj=e%31, sender j = jj<i ? jj : jj+1.
// h1 = relu(S[j]+R[i]), S = x@W1[k][0:4]+b1 (senders first), R = x@W1[k][4:8].
// msg = relu(h1@W2[k]+b2[k]); agg[i] += msg*g[e,k]
// aug=[agg|x|0pad] -> relu(@[Wo1_agg;Wo1_x]+bo1) -> relu(@Wo2+bo2) -> @Wo3+bo3; out=x+pred.
// GEMMs via v_mfma_f32_16x16x32_f16. Structure = R5 champion (2048 x 256).
// CHANGE vs R5: fragment packing via bitcast chain (pack8) instead of a
// f16x8/f16x2 union — the union defeated SROA and forced fragments to scratch
// (WRITE_SIZE 114MB vs 1MB output). All fragment state now pure VGPR.
// MFMA layout (16x16x32): A: row=l&15, k=8*(l>>4)+e; B: col=l&15, k=8*(l>>4)+e;
//                         D: col=l&15, row=4*(l>>4)+reg.

typedef _Float16     f16x8 __attribute__((ext_vector_type(8)));
typedef float        f32x4 __attribute__((ext_vector_type(4)));
typedef unsigned int u32x4 __attribute__((ext_vector_type(4)));

static __device__ __forceinline__ f16x8 pack8(float a0, float b0, float a1, float b1,
                                              float a2, float b2, float a3, float b3)
{
    u32x4 u;
    u.x = __builtin_bit_cast(unsigned int, __builtin_amdgcn_cvt_pkrtz(a0, b0));
    u.y = __builtin_bit_cast(unsigned int, __builtin_amdgcn_cvt_pkrtz(a1, b1));
    u.z = __builtin_bit_cast(unsigned int, __builtin_amdgcn_cvt_pkrtz(a2, b2));
    u.w = __builtin_bit_cast(unsigned int, __builtin_amdgcn_cvt_pkrtz(a3, b3));
    return __builtin_bit_cast(f16x8, u);
}

__global__ __launch_bounds__(256, 3)
void nri_fused(const float* __restrict__ inputs,
               const float* __restrict__ rgraph,
               const float* __restrict__ W1,  const float* __restrict__ b1,
               const float* __restrict__ W2,  const float* __restrict__ b2,
               const float* __restrict__ Wo1, const float* __restrict__ bo1,
               const float* __restrict__ Wo2, const float* __restrict__ bo2,
               const float* __restrict__ Wo3, const float* __restrict__ bo3,
               float* __restrict__ out)
{
    // floats: x 0(128) | g 128(1984) | S 2112(32x68) | R 4288(32x68) |
    //         aug 6464(32x100) | h_l 9664(32x136 halves = 2176 fl) = 11840 (47.4KB)
    // p2 overlays S/R: 2112(32x132=4224 <= 4352)
    __shared__ float smem[11840];
    float* x_l = smem;
    float* g_l = smem + 128;
    float* S   = smem + 2112;
    float* R   = smem + 4288;
    float* aug = smem + 6464;
    _Float16* h_l = reinterpret_cast<_Float16*>(smem + 9664);
    float* p2  = smem + 2112;

    const int tid  = threadIdx.x;
    const int b    = blockIdx.x >> 8;
    const int t    = blockIdx.x & 255;
    const int w    = tid >> 6;
    const int lane = tid & 63;
    const int q    = lane & 15;
    const int g4   = lane >> 4;

    // ---- stage x, g, aug x-part + zero pad (cols 64..95) ----
    if (tid < 32)
        reinterpret_cast<float4*>(x_l)[tid] =
            *reinterpret_cast<const float4*>(inputs + ((size_t)(b * 32 + tid) * 256 + t) * 4);
    for (int idx = tid; idx < 1984; idx += 256) g_l[idx] = rgraph[idx];
    for (int idx = tid; idx < 1024; idx += 256) {
        const int n = idx >> 5, c = idx & 31;
        aug[n * 100 + 64 + c] =
            (c < 4) ? inputs[((size_t)(b * 32 + n) * 256 + t) * 4 + c] : 0.f;
    }

    float agg_acc[8];
    #pragma unroll
    for (int rr = 0; rr < 8; ++rr) agg_acc[rr] = 0.f;

    for (int k = 0; k < 2; ++k) {
        __syncthreads();   // x_l ready (k=0); S/R free for restage (k=1)
        // ---- stage S (sender proj + b1), R (receiver proj), stride 68 ----
        for (int idx = tid; idx < 2048; idx += 256) {
            const int j = idx >> 6, kk = idx & 63;
            const float4 xj = reinterpret_cast<const float4*>(x_l)[j];
            const float* wp = W1 + k * 512 + kk;
            float s = b1[k * 64 + kk], r = 0.f;
            s = fmaf(xj.x, wp[0],   s);  r = fmaf(xj.x, wp[256], r);
            s = fmaf(xj.y, wp[64],  s);  r = fmaf(xj.y, wp[320], r);
            s = fmaf(xj.z, wp[128], s);  r = fmaf(xj.z, wp[384], r);
            s = fmaf(xj.w, wp[192], s);  r = fmaf(xj.w, wp[448], r);
            S[j * 68 + kk] = s;
            R[j * 68 + kk] = r;
        }
        // ---- W2 B-fragments + b2 (registers, static indices only) ----
        f16x8 w2f[4][2];
        float bb[4];
        #pragma unroll
        for (int n = 0; n < 4; ++n) {
            bb[n] = b2[k * 64 + 16 * n + q];
            #pragma unroll
            for (int s = 0; s < 2; ++s) {
                const int ka = 32 * s + 8 * g4;
                const float* wp = W2 + k * 4096 + 16 * n + q;
                w2f[n][s] = pack8(wp[(ka + 0) * 64], wp[(ka + 1) * 64],
                                  wp[(ka + 2) * 64], wp[(ka + 3) * 64],
                                  wp[(ka + 4) * 64], wp[(ka + 5) * 64],
                                  wp[(ka + 6) * 64], wp[(ka + 7) * 64]);
            }
        }
        __syncthreads();   // S,R visible

        // ---- per-receiver edge GEMM, no barriers ----
        #pragma unroll
        for (int rr = 0; rr < 8; ++rr) {
            const int i = w * 8 + rr;
            float4 Rv[2][2];
            #pragma unroll
            for (int s = 0; s < 2; ++s) {
                const float* rp = R + i * 68 + 32 * s + 8 * g4;
                Rv[s][0] = *reinterpret_cast<const float4*>(rp);
                Rv[s][1] = *reinterpret_cast<const float4*>(rp + 4);
            }
            f16x8 af[2][2];
            #pragma unroll
            for (int m = 0; m < 2; ++m) {
                const int r = 16 * m + q;
                const int j = (r == 31) ? 0 : ((r < i) ? r : r + 1);
                #pragma unroll
                for (int s = 0; s < 2; ++s) {
                    const float* sp = S + j * 68 + 32 * s + 8 * g4;
                    const float4 s0 = *reinterpret_cast<const float4*>(sp);
                    const float4 s1 = *reinterpret_cast<const float4*>(sp + 4);
                    af[m][s] = pack8(
                        fmaxf(s0.x + Rv[s][0].x, 0.f), fmaxf(s0.y + Rv[s][0].y, 0.f),
                        fmaxf(s0.z + Rv[s][0].z, 0.f), fmaxf(s0.w + Rv[s][0].w, 0.f),
                        fmaxf(s1.x + Rv[s][1].x, 0.f), fmaxf(s1.y + Rv[s][1].y, 0.f),
                        fmaxf(s1.z + Rv[s][1].z, 0.f), fmaxf(s1.w + Rv[s][1].w, 0.f));
                }
            }
            f32x4 acc[2][4];
            #pragma unroll
            for (int m = 0; m < 2; ++m)
                #pragma unroll
                for (int n = 0; n < 4; ++n) {
                    acc[m][n][0] = bb[n]; acc[m][n][1] = bb[n];
                    acc[m][n][2] = bb[n]; acc[m][n][3] = bb[n];
                }
            #pragma unroll
            for (int s = 0; s < 2; ++s)
                #pragma unroll
                for (int m = 0; m < 2; ++m)
                    #pragma unroll
                    for (int n = 0; n < 4; ++n)
                        acc[m][n] = __builtin_amdgcn_mfma_f32_16x16x32_f16(
                            af[m][s], w2f[n][s], acc[m][n], 0, 0, 0);
            float part[4] = {0.f, 0.f, 0.f, 0.f};
            #pragma unroll
            for (int m = 0; m < 2; ++m)
                #pragma unroll
                for (int reg = 0; reg < 4; ++reg) {
                    const int row = 16 * m + 4 * g4 + reg;
                    const float gv = (row < 31) ? g_l[(31 * i + row) * 2 + k] : 0.f;
                    #pragma unroll
                    for (int n = 0; n < 4; ++n)
                        part[n] = fmaf(fmaxf(acc[m][n][reg], 0.f), gv, part[n]);
                }
            #pragma unroll
            for (int n = 0; n < 4; ++n) {
                part[n] += __shfl_xor(part[n], 16);
                part[n] += __shfl_xor(part[n], 32);
            }
            const float v = (g4 == 0) ? part[0] : (g4 == 1) ? part[1]
                          : (g4 == 2) ? part[2] : part[3];
            agg_acc[rr] += v;
        }
    }

    // ---- agg -> aug cols 0..63 ----
    #pragma unroll
    for (int rr = 0; rr < 8; ++rr)
        aug[(w * 8 + rr) * 100 + 16 * g4 + q] = agg_acc[rr];
    __syncthreads();

    const int c0 = 32 * w;   // wave's 32-col slice of NH=128

    // ---- node layer 1: aug(32x96) @ [Wo1_agg;Wo1_x;0] -> h (fp16, stride 136) ----
    {
        f16x8 bf[2][3];
        #pragma unroll
        for (int n = 0; n < 2; ++n)
            #pragma unroll
            for (int s = 0; s < 3; ++s) {
                const int col = c0 + 16 * n + q;
                const int ka = 32 * s + 8 * g4;
                float vv[8];
                #pragma unroll
                for (int e2 = 0; e2 < 8; ++e2) {
                    const int kx = ka + e2;
                    vv[e2] = (kx < 64) ? Wo1[(4 + kx) * 128 + col]
                           : ((kx < 68) ? Wo1[(kx - 64) * 128 + col] : 0.f);
                }
                bf[n][s] = pack8(vv[0], vv[1], vv[2], vv[3], vv[4], vv[5], vv[6], vv[7]);
            }
        f32x4 acc[2][2];
        #pragma unroll
        for (int m = 0; m < 2; ++m)
            #pragma unroll
            for (int n = 0; n < 2; ++n) {
                const float bv = bo1[c0 + 16 * n + q];
                acc[m][n][0] = bv; acc[m][n][1] = bv; acc[m][n][2] = bv; acc[m][n][3] = bv;
            }
        #pragma unroll
        for (int s = 0; s < 3; ++s) {
            f16x8 afr[2];
            #pragma unroll
            for (int m = 0; m < 2; ++m) {
                const float* ap = aug + (16 * m + q) * 100 + 32 * s + 8 * g4;
                const float4 a0 = *reinterpret_cast<const float4*>(ap);
                const float4 a1 = *reinterpret_cast<const float4*>(ap + 4);
                afr[m] = pack8(a0.x, a0.y, a0.z, a0.w, a1.x, a1.y, a1.z, a1.w);
            }
            #pragma unroll
            for (int m = 0; m < 2; ++m)
                #pragma unroll
                for (int n = 0; n < 2; ++n)
                    acc[m][n] = __builtin_amdgcn_mfma_f32_16x16x32_f16(
                        afr[m], bf[n][s], acc[m][n], 0, 0, 0);
        }
        #pragma unroll
        for (int m = 0; m < 2; ++m)
            #pragma unroll
            for (int n = 0; n < 2; ++n)
                #pragma unroll
                for (int reg = 0; reg < 4; ++reg) {
                    const int row = 16 * m + 4 * g4 + reg;
                    h_l[row * 136 + c0 + 16 * n + q] = (_Float16)fmaxf(acc[m][n][reg], 0.f);
                }
    }
    __syncthreads();

    // ---- node layer 2: h(32x128 fp16) @ Wo2 -> p2 (fp32, stride 132) ----
    {
        f16x8 bf[2][4];
        #pragma unroll
        for (int n = 0; n < 2; ++n)
            #pragma unroll
            for (int s = 0; s < 4; ++s) {
                const int col = c0 + 16 * n + q;
                const int ka = 32 * s + 8 * g4;
                bf[n][s] = pack8(Wo2[(ka + 0) * 128 + col], Wo2[(ka + 1) * 128 + col],
                                 Wo2[(ka + 2) * 128 + col], Wo2[(ka + 3) * 128 + col],
                                 Wo2[(ka + 4) * 128 + col], Wo2[(ka + 5) * 128 + col],
                                 Wo2[(ka + 6) * 128 + col], Wo2[(ka + 7) * 128 + col]);
            }
        f32x4 acc[2][2];
        #pragma unroll
        for (int m = 0; m < 2; ++m)
            #pragma unroll
            for (int n = 0; n < 2; ++n) {
                const float bv = bo2[c0 + 16 * n + q];
                acc[m][n][0] = bv; acc[m][n][1] = bv; acc[m][n][2] = bv; acc[m][n][3] = bv;
            }
        #pragma unroll
        for (int s = 0; s < 4; ++s) {
            f16x8 afr[2];
            #pragma unroll
            for (int m = 0; m < 2; ++m)
                afr[m] = *reinterpret_cast<const f16x8*>(
                    h_l + (16 * m + q) * 136 + 32 * s + 8 * g4);
            #pragma unroll
            for (int m = 0; m < 2; ++m)
                #pragma unroll
                for (int n = 0; n < 2; ++n)
                    acc[m][n] = __builtin_amdgcn_mfma_f32_16x16x32_f16(
                        afr[m], bf[n][s], acc[m][n], 0, 0, 0);
        }
        #pragma unroll
        for (int m = 0; m < 2; ++m)
            #pragma unroll
            for (int n = 0; n < 2; ++n)
                #pragma unroll
                for (int reg = 0; reg < 4; ++reg) {
                    const int row = 16 * m + 4 * g4 + reg;
                    p2[row * 132 + c0 + 16 * n + q] = fmaxf(acc[m][n][reg], 0.f);
                }
    }
    __syncthreads();

    // ---- layer 3 (fp32 VALU) + residual + store (skip t == 255) ----
    if (tid < 128 && t < 255) {
        const int rr3 = tid >> 2;
        const int dd  = tid & 3;
        float a0 = 0.f, a1 = 0.f, a2 = 0.f, a3 = 0.f;
        const float* pr = p2 + rr3 * 132;
        for (int d = 0; d < 128; d += 4) {
            a0 = fmaf(pr[d + 0], Wo3[(d + 0) * 4 + dd], a0);
            a1 = fmaf(pr[d + 1], Wo3[(d + 1) * 4 + dd], a1);
            a2 = fmaf(pr[d + 2], Wo3[(d + 2) * 4 + dd], a2);
            a3 = fmaf(pr[d + 3], Wo3[(d + 3) * 4 + dd], a3);
        }
        const float pred = ((a0 + a1) + (a2 + a3)) + bo3[dd];
        out[((size_t)(b * 32 + rr3) * 255 + t) * 4 + dd] = x_l[rr3 * 4 + dd] + pred;
    }
}

__global__ void copy_relgraph(const float* __restrict__ g, float* __restrict__ out2)
{
    const int idx = blockIdx.x * 256 + threadIdx.x;
    if (idx < 15872) out2[idx] = g[idx % 1984];
}

extern "C" void kernel_launch(void* const* d_in, const int* in_sizes, int n_in,
                              void* d_out, int out_size, void* d_ws, size_t ws_size,
                              hipStream_t stream)
{
    (void)in_sizes; (void)n_in; (void)d_ws; (void)ws_size; (void)out_size;
    const float* inputs    = (const float*)d_in[0];
    const float* rel_graph = (const float*)d_in[3];
    const float* W1  = (const float*)d_in[4];
    const float* b1  = (const float*)d_in[5];
    const float* W2  = (const float*)d_in[6];
    const float* b2  = (const float*)d_in[7];
    const float* Wo1 = (const float*)d_in[8];
    const float* bo1 = (const float*)d_in[9];
    const float* Wo2 = (const float*)d_in[10];
    const float* bo2 = (const float*)d_in[11];
    const float* Wo3 = (const float*)d_in[12];
    const float* bo3 = (const float*)d_in[13];
    float* out = (float*)d_out;

    nri_fused<<<2048, 256, 0, stream>>>(inputs, rel_graph, W1, b1, W2, b2,
                                        Wo1, bo1, Wo2, bo2, Wo3, bo3, out);
    copy_relgraph<<<62, 256, 0, stream>>>(rel_graph, out + 261120);
}

// Round 13
// 183.589 us; speedup vs baseline: 2.1409x; 1.4018x over previous
//
#include <hip/hip_runtime.h>

// NRI MLP decoder, single step. B=8, N=32, T=256, D=4, E=992, K=2, H=64, M=64, NH=128.
// Edge e: receiver i=e/31, jj=e%31, sender j = jj<i ? jj : jj+1.
// h1 = relu(S[j]+R[i]), S = x@W1[k][0:4]+b1 (senders first), R = x@W1[k][4:8].
// msg = relu(h1@W2[k]+b2[k]); agg[i] += msg*g[e,k]
// aug=[agg|x|0pad] -> relu(@[Wo1_agg;Wo1_x]+bo1) -> relu(@Wo2+bo2) -> @Wo3+bo3; out=x+pred.
// GEMMs via v_mfma_f32_16x16x32_f16. Structure = R5/R12 champion (2048 x 256, lb(256,3)).
// CHANGE vs R12: W2 B-fragments come from an LDS-staged transposed fp16 copy
// (W2T[m][kk], stride 72 halves: 16B-aligned ds_read_b128, <=2-way banks) instead
// of per-lane register hoards. lb(256,3) caps VGPR at 84; the hoisted w2f (32 regs)
// was spilling to scratch every k (WRITE_SIZE 127MB vs 1MB output). W2T overlays
// h_l (edge phase vs node phase lifetimes). Peak live regs now ~60 < 84 -> no spill.
// MFMA layout (16x16x32): A: row=l&15, k=8*(l>>4)+e; B: col=l&15, k=8*(l>>4)+e;
//                         D: col=l&15, row=4*(l>>4)+reg.

typedef _Float16     f16x8 __attribute__((ext_vector_type(8)));
typedef float        f32x4 __attribute__((ext_vector_type(4)));
typedef unsigned int u32x4 __attribute__((ext_vector_type(4)));

static __device__ __forceinline__ f16x8 pack8(float a0, float b0, float a1, float b1,
                                              float a2, float b2, float a3, float b3)
{
    u32x4 u;
    u.x = __builtin_bit_cast(unsigned int, __builtin_amdgcn_cvt_pkrtz(a0, b0));
    u.y = __builtin_bit_cast(unsigned int, __builtin_amdgcn_cvt_pkrtz(a1, b1));
    u.z = __builtin_bit_cast(unsigned int, __builtin_amdgcn_cvt_pkrtz(a2, b2));
    u.w = __builtin_bit_cast(unsigned int, __builtin_amdgcn_cvt_pkrtz(a3, b3));
    return __builtin_bit_cast(f16x8, u);
}

__global__ __launch_bounds__(256, 3)
void nri_fused(const float* __restrict__ inputs,
               const float* __restrict__ rgraph,
               const float* __restrict__ W1,  const float* __restrict__ b1,
               const float* __restrict__ W2,  const float* __restrict__ b2,
               const float* __restrict__ Wo1, const float* __restrict__ bo1,
               const float* __restrict__ Wo2, const float* __restrict__ bo2,
               const float* __restrict__ Wo3, const float* __restrict__ bo3,
               float* __restrict__ out)
{
    // floats: x 0(128) | g 128(1984) | S 2112(32x68) | R 4288(32x68) |
    //         aug 6464(32x100) | w2t 9664(64x72 halves = 2304 fl) = 11968 (47.9KB)
    // overlays: h_l (32x136 halves = 2176 fl) @9664 (node phase; w2t dead then)
    //           p2 (32x132 = 4224 fl) @2112 (node phase; S/R dead then)
    __shared__ float smem[11968];
    float* x_l = smem;
    float* g_l = smem + 128;
    float* S   = smem + 2112;
    float* R   = smem + 4288;
    float* aug = smem + 6464;
    _Float16* w2t = reinterpret_cast<_Float16*>(smem + 9664);
    _Float16* h_l = reinterpret_cast<_Float16*>(smem + 9664);
    float* p2  = smem + 2112;

    const int tid  = threadIdx.x;
    const int b    = blockIdx.x >> 8;
    const int t    = blockIdx.x & 255;
    const int w    = tid >> 6;
    const int lane = tid & 63;
    const int q    = lane & 15;
    const int g4   = lane >> 4;

    // ---- stage x, g, aug x-part + zero pad (cols 64..95) ----
    if (tid < 32)
        reinterpret_cast<float4*>(x_l)[tid] =
            *reinterpret_cast<const float4*>(inputs + ((size_t)(b * 32 + tid) * 256 + t) * 4);
    for (int idx = tid; idx < 1984; idx += 256) g_l[idx] = rgraph[idx];
    for (int idx = tid; idx < 1024; idx += 256) {
        const int n = idx >> 5, c = idx & 31;
        aug[n * 100 + 64 + c] =
            (c < 4) ? inputs[((size_t)(b * 32 + n) * 256 + t) * 4 + c] : 0.f;
    }

    float agg_acc[8];
    #pragma unroll
    for (int rr = 0; rr < 8; ++rr) agg_acc[rr] = 0.f;

    for (int k = 0; k < 2; ++k) {
        __syncthreads();   // x_l ready (k=0); S/R/w2t free for restage (k=1)
        // ---- stage S (sender proj + b1), R (receiver proj), stride 68 ----
        for (int idx = tid; idx < 2048; idx += 256) {
            const int j = idx >> 6, kk = idx & 63;
            const float4 xj = reinterpret_cast<const float4*>(x_l)[j];
            const float* wp = W1 + k * 512 + kk;
            float s = b1[k * 64 + kk], r = 0.f;
            s = fmaf(xj.x, wp[0],   s);  r = fmaf(xj.x, wp[256], r);
            s = fmaf(xj.y, wp[64],  s);  r = fmaf(xj.y, wp[320], r);
            s = fmaf(xj.z, wp[128], s);  r = fmaf(xj.z, wp[384], r);
            s = fmaf(xj.w, wp[192], s);  r = fmaf(xj.w, wp[448], r);
            S[j * 68 + kk] = s;
            R[j * 68 + kk] = r;
        }
        // ---- stage W2T[m][kk] fp16, stride 72 (coalesced global read) ----
        for (int idx = tid; idx < 4096; idx += 256) {
            const int kk = idx >> 6, m = idx & 63;
            w2t[m * 72 + kk] = (_Float16)W2[k * 4096 + idx];
        }
        float bb[4];
        #pragma unroll
        for (int n = 0; n < 4; ++n) bb[n] = b2[k * 64 + 16 * n + q];
        __syncthreads();   // S,R,w2t visible

        // ---- per-receiver edge GEMM, no barriers ----
        #pragma unroll
        for (int rr = 0; rr < 8; ++rr) {
            const int i = w * 8 + rr;
            f32x4 acc[2][4];
            #pragma unroll
            for (int m = 0; m < 2; ++m)
                #pragma unroll
                for (int n = 0; n < 4; ++n) {
                    acc[m][n][0] = bb[n]; acc[m][n][1] = bb[n];
                    acc[m][n][2] = bb[n]; acc[m][n][3] = bb[n];
                }
            #pragma unroll
            for (int s = 0; s < 2; ++s) {
                const float* rp = R + i * 68 + 32 * s + 8 * g4;
                const float4 Rv0 = *reinterpret_cast<const float4*>(rp);
                const float4 Rv1 = *reinterpret_cast<const float4*>(rp + 4);
                f16x8 af[2];
                #pragma unroll
                for (int m = 0; m < 2; ++m) {
                    const int r = 16 * m + q;
                    const int j = (r == 31) ? 0 : ((r < i) ? r : r + 1);
                    const float* sp = S + j * 68 + 32 * s + 8 * g4;
                    const float4 s0 = *reinterpret_cast<const float4*>(sp);
                    const float4 s1 = *reinterpret_cast<const float4*>(sp + 4);
                    af[m] = pack8(
                        fmaxf(s0.x + Rv0.x, 0.f), fmaxf(s0.y + Rv0.y, 0.f),
                        fmaxf(s0.z + Rv0.z, 0.f), fmaxf(s0.w + Rv0.w, 0.f),
                        fmaxf(s1.x + Rv1.x, 0.f), fmaxf(s1.y + Rv1.y, 0.f),
                        fmaxf(s1.z + Rv1.z, 0.f), fmaxf(s1.w + Rv1.w, 0.f));
                }
                #pragma unroll
                for (int n = 0; n < 4; ++n) {
                    const f16x8 wb = *reinterpret_cast<const f16x8*>(
                        w2t + (16 * n + q) * 72 + 32 * s + 8 * g4);
                    acc[0][n] = __builtin_amdgcn_mfma_f32_16x16x32_f16(
                        af[0], wb, acc[0][n], 0, 0, 0);
                    acc[1][n] = __builtin_amdgcn_mfma_f32_16x16x32_f16(
                        af[1], wb, acc[1][n], 0, 0, 0);
                }
            }
            float part[4] = {0.f, 0.f, 0.f, 0.f};
            #pragma unroll
            for (int m = 0; m < 2; ++m)
                #pragma unroll
                for (int reg = 0; reg < 4; ++reg) {
                    const int row = 16 * m + 4 * g4 + reg;
                    const float gv = (row < 31) ? g_l[(31 * i + row) * 2 + k] : 0.f;
                    #pragma unroll
                    for (int n = 0; n < 4; ++n)
                        part[n] = fmaf(fmaxf(acc[m][n][reg], 0.f), gv, part[n]);
                }
            #pragma unroll
            for (int n = 0; n < 4; ++n) {
                part[n] += __shfl_xor(part[n], 16);
                part[n] += __shfl_xor(part[n], 32);
            }
            const float v = (g4 == 0) ? part[0] : (g4 == 1) ? part[1]
                          : (g4 == 2) ? part[2] : part[3];
            agg_acc[rr] += v;
        }
    }

    // ---- agg -> aug cols 0..63 ----
    #pragma unroll
    for (int rr = 0; rr < 8; ++rr)
        aug[(w * 8 + rr) * 100 + 16 * g4 + q] = agg_acc[rr];
    __syncthreads();

    const int c0 = 32 * w;   // wave's 32-col slice of NH=128

    // ---- node layer 1: aug(32x96) @ [Wo1_agg;Wo1_x;0] -> h (fp16, stride 136) ----
    {
        f16x8 bf[2][3];
        #pragma unroll
        for (int n = 0; n < 2; ++n)
            #pragma unroll
            for (int s = 0; s < 3; ++s) {
                const int col = c0 + 16 * n + q;
                const int ka = 32 * s + 8 * g4;
                float vv[8];
                #pragma unroll
                for (int e2 = 0; e2 < 8; ++e2) {
                    const int kx = ka + e2;
                    vv[e2] = (kx < 64) ? Wo1[(4 + kx) * 128 + col]
                           : ((kx < 68) ? Wo1[(kx - 64) * 128 + col] : 0.f);
                }
                bf[n][s] = pack8(vv[0], vv[1], vv[2], vv[3], vv[4], vv[5], vv[6], vv[7]);
            }
        f32x4 acc[2][2];
        #pragma unroll
        for (int m = 0; m < 2; ++m)
            #pragma unroll
            for (int n = 0; n < 2; ++n) {
                const float bv = bo1[c0 + 16 * n + q];
                acc[m][n][0] = bv; acc[m][n][1] = bv; acc[m][n][2] = bv; acc[m][n][3] = bv;
            }
        #pragma unroll
        for (int s = 0; s < 3; ++s) {
            f16x8 afr[2];
            #pragma unroll
            for (int m = 0; m < 2; ++m) {
                const float* ap = aug + (16 * m + q) * 100 + 32 * s + 8 * g4;
                const float4 a0 = *reinterpret_cast<const float4*>(ap);
                const float4 a1 = *reinterpret_cast<const float4*>(ap + 4);
                afr[m] = pack8(a0.x, a0.y, a0.z, a0.w, a1.x, a1.y, a1.z, a1.w);
            }
            #pragma unroll
            for (int m = 0; m < 2; ++m)
                #pragma unroll
                for (int n = 0; n < 2; ++n)
                    acc[m][n] = __builtin_amdgcn_mfma_f32_16x16x32_f16(
                        afr[m], bf[n][s], acc[m][n], 0, 0, 0);
        }
        __syncthreads();   // w2t reads done everywhere before h_l overwrite
        #pragma unroll
        for (int m = 0; m < 2; ++m)
            #pragma unroll
            for (int n = 0; n < 2; ++n)
                #pragma unroll
                for (int reg = 0; reg < 4; ++reg) {
                    const int row = 16 * m + 4 * g4 + reg;
                    h_l[row * 136 + c0 + 16 * n + q] = (_Float16)fmaxf(acc[m][n][reg], 0.f);
                }
    }
    __syncthreads();

    // ---- node layer 2: h(32x128 fp16) @ Wo2 -> p2 (fp32, stride 132) ----
    {
        f16x8 bf[2][4];
        #pragma unroll
        for (int n = 0; n < 2; ++n)
            #pragma unroll
            for (int s = 0; s < 4; ++s) {
                const int col = c0 + 16 * n + q;
                const int ka = 32 * s + 8 * g4;
                bf[n][s] = pack8(Wo2[(ka + 0) * 128 + col], Wo2[(ka + 1) * 128 + col],
                                 Wo2[(ka + 2) * 128 + col], Wo2[(ka + 3) * 128 + col],
                                 Wo2[(ka + 4) * 128 + col], Wo2[(ka + 5) * 128 + col],
                                 Wo2[(ka + 6) * 128 + col], Wo2[(ka + 7) * 128 + col]);
            }
        f32x4 acc[2][2];
        #pragma unroll
        for (int m = 0; m < 2; ++m)
            #pragma unroll
            for (int n = 0; n < 2; ++n) {
                const float bv = bo2[c0 + 16 * n + q];
                acc[m][n][0] = bv; acc[m][n][1] = bv; acc[m][n][2] = bv; acc[m][n][3] = bv;
            }
        #pragma unroll
        for (int s = 0; s < 4; ++s) {
            f16x8 afr[2];
            #pragma unroll
            for (int m = 0; m < 2; ++m)
                afr[m] = *reinterpret_cast<const f16x8*>(
                    h_l + (16 * m + q) * 136 + 32 * s + 8 * g4);
            #pragma unroll
            for (int m = 0; m < 2; ++m)
                #pragma unroll
                for (int n = 0; n < 2; ++n)
                    acc[m][n] = __builtin_amdgcn_mfma_f32_16x16x32_f16(
                        afr[m], bf[n][s], acc[m][n], 0, 0, 0);
        }
        #pragma unroll
        for (int m = 0; m < 2; ++m)
            #pragma unroll
            for (int n = 0; n < 2; ++n)
                #pragma unroll
                for (int reg = 0; reg < 4; ++reg) {
                    const int row = 16 * m + 4 * g4 + reg;
                    p2[row * 132 + c0 + 16 * n + q] = fmaxf(acc[m][n][reg], 0.f);
                }
    }
    __syncthreads();

    // ---- layer 3 (fp32 VALU) + residual + store (skip t == 255) ----
    if (tid < 128 && t < 255) {
        const int rr3 = tid >> 2;
        const int dd  = tid & 3;
        float a0 = 0.f, a1 = 0.f, a2 = 0.f, a3 = 0.f;
        const float* pr = p2 + rr3 * 132;
        for (int d = 0; d < 128; d += 4) {
            a0 = fmaf(pr[d + 0], Wo3[(d + 0) * 4 + dd], a0);
            a1 = fmaf(pr[d + 1], Wo3[(d + 1) * 4 + dd], a1);
            a2 = fmaf(pr[d + 2], Wo3[(d + 2) * 4 + dd], a2);
            a3 = fmaf(pr[d + 3], Wo3[(d + 3) * 4 + dd], a3);
        }
        const float pred = ((a0 + a1) + (a2 + a3)) + bo3[dd];
        out[((size_t)(b * 32 + rr3) * 255 + t) * 4 + dd] = x_l[rr3 * 4 + dd] + pred;
    }
}

__global__ void copy_relgraph(const float* __restrict__ g, float* __restrict__ out2)
{
    const int idx = blockIdx.x * 256 + threadIdx.x;
    if (idx < 15872) out2[idx] = g[idx % 1984];
}

extern "C" void kernel_launch(void* const* d_in, const int* in_sizes, int n_in,
                              void* d_out, int out_size, void* d_ws, size_t ws_size,
                              hipStream_t stream)
{
    (void)in_sizes; (void)n_in; (void)d_ws; (void)ws_size; (void)out_size;
    const float* inputs    = (const float*)d_in[0];
    const float* rel_graph = (const float*)d_in[3];
    const float* W1  = (const float*)d_in[4];
    const float* b1  = (const float*)d_in[5];
    const float* W2  = (const float*)d_in[6];
    const float* b2  = (const float*)d_in[7];
    const float* Wo1 = (const float*)d_in[8];
    const float* bo1 = (const float*)d_in[9];
    const float* Wo2 = (const float*)d_in[10];
    const float* bo2 = (const float*)d_in[11];
    const float* Wo3 = (const float*)d_in[12];
    const float* bo3 = (const float*)d_in[13];
    float* out = (float*)d_out;

    nri_fused<<<2048, 256, 0, stream>>>(inputs, rel_graph, W1, b1, W2, b2,
                                        Wo1, bo1, Wo2, bo2, Wo3, bo3, out);
    copy_relgraph<<<62, 256, 0, stream>>>(rel_graph, out + 261120);
}